// Round 1
// baseline (309.831 us; speedup 1.0000x reference)
//
#include <hip/hip_runtime.h>
#include <cstdint>
#include <cstddef>

// ---------------------------------------------------------------------------
// NAMAttention: fused QKV/w/r projection -> per-head norm + gates ->
// A = (v*w)^T k-hat (per b,n) -> out2 = q-hat A^T * r -> out = out2 Wo^T + b.
// All heavy GEMMs in bf16 MFMA (16x16x32), fp32 accumulate. Round 0:
// m97-style 128x128 tile, BK=64, 4 waves, global_load_lds width-16 staging.
// ---------------------------------------------------------------------------

typedef __bf16 bf16x8 __attribute__((ext_vector_type(8)));
typedef float  f32x4  __attribute__((ext_vector_type(4)));
typedef unsigned short u16x8 __attribute__((ext_vector_type(8)));
typedef unsigned short u16x4 __attribute__((ext_vector_type(4)));

#define ROWS 16384      // S*B
#define DM   1024
#define NPACK 3200      // padded packed-N (3104 used)

__device__ __forceinline__ unsigned short f2bf(float f) {
  unsigned int u = __builtin_bit_cast(unsigned int, f);
  u += 0x7FFFu + ((u >> 16) & 1u);            // round-to-nearest-even
  return (unsigned short)(u >> 16);
}
__device__ __forceinline__ float bf2f(unsigned short h) {
  unsigned int u = ((unsigned int)h) << 16;
  return __builtin_bit_cast(float, u);
}
__device__ __forceinline__ float sigm(float x) { return 1.0f / (1.0f + __expf(-x)); }

// global(16B/lane) -> LDS direct copy; lds base must be wave-uniform.
__device__ __forceinline__ void gload_lds16(const void* g, void* l) {
  __builtin_amdgcn_global_load_lds((__attribute__((address_space(1))) void*)(g),
                                   (__attribute__((address_space(3))) void*)(l),
                                   16, 0, 0);
}

// ---------------- cast input to bf16 ----------------
__global__ __launch_bounds__(256) void k_cast_x(const float* __restrict__ X,
                                                unsigned short* __restrict__ Xb) {
  size_t i = ((size_t)blockIdx.x * 256 + threadIdx.x) * 8;
  f32x4 a = *(const f32x4*)(X + i);
  f32x4 b = *(const f32x4*)(X + i + 4);
  u16x8 o;
  o[0] = f2bf(a[0]); o[1] = f2bf(a[1]); o[2] = f2bf(a[2]); o[3] = f2bf(a[3]);
  o[4] = f2bf(b[0]); o[5] = f2bf(b[1]); o[6] = f2bf(b[2]); o[7] = f2bf(b[3]);
  *(u16x8*)(Xb + i) = o;
}

// ---------------- pack weights (bf16) + packed bias ----------------
// Wpack rows: [0,1024) Wq | [1024,2048) Wk | [2048,3072) Wv | [3072,3088) Ww
//             | [3088,3104) Wr | [3104,3200) zeros.   Wob: Wo (1024 rows).
__global__ __launch_bounds__(256) void k_pack_w(
    const float* __restrict__ Wq, const float* __restrict__ Wk, const float* __restrict__ Wv,
    const float* __restrict__ Wo, const float* __restrict__ Ww, const float* __restrict__ Wr,
    const float* __restrict__ bq, const float* __restrict__ bk, const float* __restrict__ bv,
    const float* __restrict__ bw, const float* __restrict__ br,
    unsigned short* __restrict__ Wpack, float* __restrict__ biasP,
    unsigned short* __restrict__ Wob) {
  int r = blockIdx.x, t = threadIdx.x;
  const float* src; float bias = 0.0f; unsigned short* dst;
  if (r < 1024)      { src = Wq + (size_t)r * DM;          bias = bq[r];        dst = Wpack + (size_t)r * DM; }
  else if (r < 2048) { src = Wk + (size_t)(r - 1024) * DM; bias = bk[r - 1024]; dst = Wpack + (size_t)r * DM; }
  else if (r < 3072) { src = Wv + (size_t)(r - 2048) * DM; bias = bv[r - 2048]; dst = Wpack + (size_t)r * DM; }
  else if (r < 3088) { src = Ww + (size_t)(r - 3072) * DM; bias = bw[r - 3072]; dst = Wpack + (size_t)r * DM; }
  else if (r < 3104) { src = Wr + (size_t)(r - 3088) * DM; bias = br[r - 3088]; dst = Wpack + (size_t)r * DM; }
  else if (r < 3200) { src = nullptr;                                           dst = Wpack + (size_t)r * DM; }
  else               { src = Wo + (size_t)(r - 3200) * DM;                      dst = Wob + (size_t)(r - 3200) * DM; }
  int c = t * 4;
  u16x4 o;
  if (src) {
    f32x4 v = *(const f32x4*)(src + c);
    o[0] = f2bf(v[0]); o[1] = f2bf(v[1]); o[2] = f2bf(v[2]); o[3] = f2bf(v[3]);
  } else {
    o[0] = 0; o[1] = 0; o[2] = 0; o[3] = 0;
  }
  *(u16x4*)(dst + c) = o;
  if (t == 0 && r < 3200) biasP[r] = bias;
}

// ---------------- fused QKV + w/r logits GEMM ----------------
// Y[row, col] = X[row,:] . Wpack[col,:] + biasP[col]; routed to Qb/Kb/Vb (bf16)
// and WRf (fp32 logits, cols 3072..3103 -> 32 per row).
__global__ __launch_bounds__(256, 2) void k_gemm_qkv(
    const unsigned short* __restrict__ Xb, const unsigned short* __restrict__ Wpack,
    const float* __restrict__ biasP,
    unsigned short* __restrict__ Qb, unsigned short* __restrict__ Kb,
    unsigned short* __restrict__ Vb, float* __restrict__ WRf) {
  __shared__ __bf16 smA[128 * 64];
  __shared__ __bf16 smB[128 * 64];
  int t = threadIdx.x, lane = t & 63, wid = t >> 6;
  int m0 = (blockIdx.x & 127) * 128;
  int n0 = (blockIdx.x >> 7) * 128;
  int wr = wid >> 1, wc = wid & 1;
  f32x4 acc[4][4];
#pragma unroll
  for (int i = 0; i < 4; i++)
#pragma unroll
    for (int j = 0; j < 4; j++) acc[i][j] = (f32x4){0.f, 0.f, 0.f, 0.f};
  int srow = wid * 32;
  int lrow = lane >> 3, lcol = (lane & 7) * 8;

  for (int kt = 0; kt < DM; kt += 64) {
#pragma unroll
    for (int c = 0; c < 4; c++) {
      int r = srow + c * 8 + lrow;
      gload_lds16(Xb + (size_t)(m0 + r) * DM + kt + lcol, (void*)(smA + (srow + c * 8) * 64));
      gload_lds16(Wpack + (size_t)(n0 + r) * DM + kt + lcol, (void*)(smB + (srow + c * 8) * 64));
    }
    __syncthreads();
#pragma unroll
    for (int kk = 0; kk < 64; kk += 32) {
      bf16x8 fa[4], fb[4];
#pragma unroll
      for (int mi = 0; mi < 4; mi++)
        fa[mi] = *(const bf16x8*)(smA + (wr * 64 + mi * 16 + (lane & 15)) * 64 + kk + 8 * (lane >> 4));
#pragma unroll
      for (int ni = 0; ni < 4; ni++)
        fb[ni] = *(const bf16x8*)(smB + (wc * 64 + ni * 16 + (lane & 15)) * 64 + kk + 8 * (lane >> 4));
#pragma unroll
      for (int mi = 0; mi < 4; mi++)
#pragma unroll
        for (int ni = 0; ni < 4; ni++)
          acc[mi][ni] = __builtin_amdgcn_mfma_f32_16x16x32_bf16(fa[mi], fb[ni], acc[mi][ni], 0, 0, 0);
    }
    __syncthreads();
  }
  // epilogue: C/D layout col=lane&15, row=4*(lane>>4)+e  [HW-verified m89]
#pragma unroll
  for (int mi = 0; mi < 4; mi++) {
#pragma unroll
    for (int e = 0; e < 4; e++) {
      int row = m0 + wr * 64 + mi * 16 + 4 * (lane >> 4) + e;
#pragma unroll
      for (int ni = 0; ni < 4; ni++) {
        int col = n0 + wc * 64 + ni * 16 + (lane & 15);
        float v = acc[mi][ni][e] + biasP[col];
        if (col < 1024)      Qb[(size_t)row * DM + col] = f2bf(v);
        else if (col < 2048) Kb[(size_t)row * DM + col - 1024] = f2bf(v);
        else if (col < 3072) Vb[(size_t)row * DM + col - 2048] = f2bf(v);
        else if (col < 3104) WRf[(size_t)row * 32 + col - 3072] = v;
      }
    }
  }
}

// ---------------- per-head normalize q,k ; v *= sigmoid(w) ----------------
__global__ __launch_bounds__(256) void k_postproc(unsigned short* __restrict__ Qb,
                                                  unsigned short* __restrict__ Kb,
                                                  unsigned short* __restrict__ Vb,
                                                  const float* __restrict__ WRf) {
  int row = blockIdx.x, t = threadIdx.x;
  unsigned short* base; int tt;
  if (t < 128) { base = Qb; tt = t; } else { base = Kb; tt = t - 128; }
  size_t off = (size_t)row * DM + tt * 8;
  u16x8 v = *(const u16x8*)(base + off);
  float f[8]; float ssq = 0.f;
#pragma unroll
  for (int e = 0; e < 8; e++) { f[e] = bf2f(v[e]); ssq += f[e] * f[e]; }
  ssq += __shfl_xor(ssq, 1);
  ssq += __shfl_xor(ssq, 2);
  ssq += __shfl_xor(ssq, 4);          // 8 lanes = one 64-elem head
  float scale = 1.0f / fmaxf(sqrtf(ssq), 1e-12f);
  u16x8 o;
#pragma unroll
  for (int e = 0; e < 8; e++) o[e] = f2bf(f[e] * scale);
  *(u16x8*)(base + off) = o;
  if (t < 128) {
    int h = t >> 3;
    float w = sigm(WRf[(size_t)row * 32 + h]);
    size_t voff = (size_t)row * DM + t * 8;
    u16x8 vv = *(const u16x8*)(Vb + voff);
    u16x8 ov;
#pragma unroll
    for (int e = 0; e < 8; e++) ov[e] = f2bf(bf2f(vv[e]) * w);
    *(u16x8*)(Vb + voff) = ov;
  }
}

// ---------------- A[b,n,i,j] = sum_s vw[s,(b,n),i] * khat[s,(b,n),j] ----------------
// one block per (b,n); 64x64 output, K=2048.
__global__ __launch_bounds__(256, 2) void k_gemm_A(const unsigned short* __restrict__ Kb,
                                                   const unsigned short* __restrict__ Vb,
                                                   float* __restrict__ Aout,
                                                   unsigned short* __restrict__ Abf) {
  __shared__ __bf16 sK[64 * 64];
  __shared__ __bf16 sV[64 * 64];
  int t = threadIdx.x, lane = t & 63, wid = t >> 6;
  int bn = blockIdx.x;             // b*16 + n
  int b = bn >> 4, n = bn & 15;
  f32x4 acc[4];
#pragma unroll
  for (int j = 0; j < 4; j++) acc[j] = (f32x4){0.f, 0.f, 0.f, 0.f};
  int lrow = lane >> 3, lcol = (lane & 7) * 8;

  for (int st = 0; st < 2048; st += 64) {
#pragma unroll
    for (int c = 0; c < 2; c++) {
      int r0 = wid * 16 + c * 8;
      size_t g = ((size_t)(st + r0 + lrow) * 8 + b) * DM + n * 64 + lcol;
      gload_lds16(Kb + g, (void*)(sK + r0 * 64));
      gload_lds16(Vb + g, (void*)(sV + r0 * 64));
    }
    __syncthreads();
#pragma unroll
    for (int kk = 0; kk < 64; kk += 32) {
      bf16x8 av, bv[4];
#pragma unroll
      for (int e = 0; e < 8; e++)
        av[e] = sV[(kk + 8 * (lane >> 4) + e) * 64 + wid * 16 + (lane & 15)];
#pragma unroll
      for (int jn = 0; jn < 4; jn++)
#pragma unroll
        for (int e = 0; e < 8; e++)
          bv[jn][e] = sK[(kk + 8 * (lane >> 4) + e) * 64 + jn * 16 + (lane & 15)];
#pragma unroll
      for (int jn = 0; jn < 4; jn++)
        acc[jn] = __builtin_amdgcn_mfma_f32_16x16x32_bf16(av, bv[jn], acc[jn], 0, 0, 0);
    }
    __syncthreads();
  }
  float* Ao = Aout + (size_t)bn * 4096;
  unsigned short* Ab = Abf + (size_t)bn * 4096;
#pragma unroll
  for (int jn = 0; jn < 4; jn++) {
#pragma unroll
    for (int e = 0; e < 4; e++) {
      int i = wid * 16 + 4 * (lane >> 4) + e;
      int j = jn * 16 + (lane & 15);
      Ao[i * 64 + j] = acc[jn][e];
      Ab[i * 64 + j] = f2bf(acc[jn][e]);
    }
  }
}

// ---------------- out2[row, n*64+i] = r * sum_j qhat[row, n*64+j]*A[bn,i,j] ----------------
__global__ __launch_bounds__(256, 2) void k_gemm_o2(const unsigned short* __restrict__ Qb,
                                                    const unsigned short* __restrict__ Abf,
                                                    const float* __restrict__ WRf,
                                                    unsigned short* __restrict__ Ob) {
  __shared__ __bf16 sQ[128 * 64];
  __shared__ __bf16 sA[64 * 64];
  int t = threadIdx.x, lane = t & 63, wid = t >> 6;
  int bn = blockIdx.x & 127, stile = blockIdx.x >> 7;
  int b = bn >> 4, n = bn & 15;
  int s0 = stile * 128;
  int lrow = lane >> 3, lcol = (lane & 7) * 8;
#pragma unroll
  for (int c = 0; c < 4; c++) {
    int r0 = wid * 32 + c * 8;
    gload_lds16(Qb + ((size_t)(s0 + r0 + lrow) * 8 + b) * DM + n * 64 + lcol,
                (void*)(sQ + r0 * 64));
  }
#pragma unroll
  for (int c = 0; c < 2; c++) {
    int r0 = wid * 16 + c * 8;
    gload_lds16(Abf + (size_t)bn * 4096 + (size_t)(r0 + lrow) * 64 + lcol,
                (void*)(sA + r0 * 64));
  }
  __syncthreads();
  f32x4 acc[2][4];
#pragma unroll
  for (int i = 0; i < 2; i++)
#pragma unroll
    for (int j = 0; j < 4; j++) acc[i][j] = (f32x4){0.f, 0.f, 0.f, 0.f};
#pragma unroll
  for (int kk = 0; kk < 64; kk += 32) {
    bf16x8 aq[2], bA[4];
#pragma unroll
    for (int mi = 0; mi < 2; mi++)
      aq[mi] = *(const bf16x8*)(sQ + (wid * 32 + mi * 16 + (lane & 15)) * 64 + kk + 8 * (lane >> 4));
#pragma unroll
    for (int ni = 0; ni < 4; ni++)
      bA[ni] = *(const bf16x8*)(sA + (ni * 16 + (lane & 15)) * 64 + kk + 8 * (lane >> 4));
#pragma unroll
    for (int mi = 0; mi < 2; mi++)
#pragma unroll
      for (int ni = 0; ni < 4; ni++)
        acc[mi][ni] = __builtin_amdgcn_mfma_f32_16x16x32_bf16(aq[mi], bA[ni], acc[mi][ni], 0, 0, 0);
  }
#pragma unroll
  for (int mi = 0; mi < 2; mi++) {
#pragma unroll
    for (int e = 0; e < 4; e++) {
      int srow = wid * 32 + mi * 16 + 4 * (lane >> 4) + e;
      size_t row = (size_t)(s0 + srow) * 8 + b;
      float rv = sigm(WRf[row * 32 + 16 + n]);
#pragma unroll
      for (int ni = 0; ni < 4; ni++)
        Ob[row * DM + n * 64 + ni * 16 + (lane & 15)] = f2bf(acc[mi][ni][e] * rv);
    }
  }
}

// ---------------- final projection: Out = Ob @ Wo^T + bo (fp32 out) ----------------
__global__ __launch_bounds__(256, 2) void k_gemm_out(const unsigned short* __restrict__ Ob,
                                                     const unsigned short* __restrict__ Wob,
                                                     const float* __restrict__ bo,
                                                     float* __restrict__ Out) {
  __shared__ __bf16 smA[128 * 64];
  __shared__ __bf16 smB[128 * 64];
  int t = threadIdx.x, lane = t & 63, wid = t >> 6;
  int m0 = (blockIdx.x & 127) * 128;
  int n0 = (blockIdx.x >> 7) * 128;
  int wr = wid >> 1, wc = wid & 1;
  f32x4 acc[4][4];
#pragma unroll
  for (int i = 0; i < 4; i++)
#pragma unroll
    for (int j = 0; j < 4; j++) acc[i][j] = (f32x4){0.f, 0.f, 0.f, 0.f};
  int srow = wid * 32;
  int lrow = lane >> 3, lcol = (lane & 7) * 8;

  for (int kt = 0; kt < DM; kt += 64) {
#pragma unroll
    for (int c = 0; c < 4; c++) {
      int r = srow + c * 8 + lrow;
      gload_lds16(Ob + (size_t)(m0 + r) * DM + kt + lcol, (void*)(smA + (srow + c * 8) * 64));
      gload_lds16(Wob + (size_t)(n0 + r) * DM + kt + lcol, (void*)(smB + (srow + c * 8) * 64));
    }
    __syncthreads();
#pragma unroll
    for (int kk = 0; kk < 64; kk += 32) {
      bf16x8 fa[4], fb[4];
#pragma unroll
      for (int mi = 0; mi < 4; mi++)
        fa[mi] = *(const bf16x8*)(smA + (wr * 64 + mi * 16 + (lane & 15)) * 64 + kk + 8 * (lane >> 4));
#pragma unroll
      for (int ni = 0; ni < 4; ni++)
        fb[ni] = *(const bf16x8*)(smB + (wc * 64 + ni * 16 + (lane & 15)) * 64 + kk + 8 * (lane >> 4));
#pragma unroll
      for (int mi = 0; mi < 4; mi++)
#pragma unroll
        for (int ni = 0; ni < 4; ni++)
          acc[mi][ni] = __builtin_amdgcn_mfma_f32_16x16x32_bf16(fa[mi], fb[ni], acc[mi][ni], 0, 0, 0);
    }
    __syncthreads();
  }
#pragma unroll
  for (int mi = 0; mi < 4; mi++) {
#pragma unroll
    for (int e = 0; e < 4; e++) {
      int row = m0 + wr * 64 + mi * 16 + 4 * (lane >> 4) + e;
#pragma unroll
      for (int ni = 0; ni < 4; ni++) {
        int col = n0 + wc * 64 + ni * 16 + (lane & 15);
        Out[(size_t)row * DM + col] = acc[mi][ni][e] + bo[col];
      }
    }
  }
}

// ---------------------------------------------------------------------------
extern "C" void kernel_launch(void* const* d_in, const int* in_sizes, int n_in,
                              void* d_out, int out_size, void* d_ws, size_t ws_size,
                              hipStream_t stream) {
  (void)in_sizes; (void)n_in; (void)out_size; (void)ws_size;
  const float* X  = (const float*)d_in[0];
  const float* Wq = (const float*)d_in[1];  const float* bq = (const float*)d_in[2];
  const float* Wk = (const float*)d_in[3];  const float* bk = (const float*)d_in[4];
  const float* Wv = (const float*)d_in[5];  const float* bv = (const float*)d_in[6];
  const float* Wo = (const float*)d_in[7];  const float* bo = (const float*)d_in[8];
  const float* Ww = (const float*)d_in[9];  const float* bw = (const float*)d_in[10];
  const float* Wr = (const float*)d_in[11]; const float* br = (const float*)d_in[12];

  char* ws = (char*)d_ws;
  // layout (bytes). Abf aliases Wpack (Wpack dead after k_gemm_qkv);
  // Ob aliases Xb (Xb dead after k_gemm_qkv). Peak ~138.3 MiB.
  unsigned short* Wpack = (unsigned short*)(ws + 0);
  unsigned short* Abf   = (unsigned short*)(ws + 0);          // 1 MiB, after qkv
  float*          biasP = (float*)(ws + 6553600);
  unsigned short* Wob   = (unsigned short*)(ws + 6566400);
  unsigned short* Xb    = (unsigned short*)(ws + 8663552);
  unsigned short* Ob    = Xb;
  unsigned short* Qb    = (unsigned short*)(ws + 42217984);
  unsigned short* Kb    = (unsigned short*)(ws + 75772416);
  unsigned short* Vb    = (unsigned short*)(ws + 109326848);
  float*          WRf   = (float*)(ws + 142881280);

  float* Out0 = (float*)d_out;
  float* Aout = Out0 + (size_t)ROWS * DM;   // second tuple output

  k_cast_x<<<dim3(8192), dim3(256), 0, stream>>>(X, Xb);
  k_pack_w<<<dim3(4224), dim3(256), 0, stream>>>(Wq, Wk, Wv, Wo, Ww, Wr,
                                                 bq, bk, bv, bw, br, Wpack, biasP, Wob);
  k_gemm_qkv<<<dim3(128 * 25), dim3(256), 0, stream>>>(Xb, Wpack, biasP, Qb, Kb, Vb, WRf);
  k_postproc<<<dim3(ROWS), dim3(256), 0, stream>>>(Qb, Kb, Vb, WRf);
  k_gemm_A<<<dim3(128), dim3(256), 0, stream>>>(Kb, Vb, Aout, Abf);
  k_gemm_o2<<<dim3(2048), dim3(256), 0, stream>>>(Qb, Abf, WRf, Ob);
  k_gemm_out<<<dim3(128 * 8), dim3(256), 0, stream>>>(Ob, Wob, bo, Out0);
}